// Round 6
// baseline (321.978 us; speedup 1.0000x reference)
//
#include <hip/hip_runtime.h>
#include <hip/hip_bf16.h>

// Problem: B=4, T=2048, C=1024, H=16, D=64
#define Bsz 4
#define Tsz 2048
#define Csz 1024
#define NH  16
#define HD  64
#define NT  (Bsz * Tsz)          // 8192 rows

typedef unsigned short u16;
typedef unsigned int   u32;
typedef u16   u16x8  __attribute__((ext_vector_type(8)));
typedef u16   u16x4  __attribute__((ext_vector_type(4)));
typedef u32   u32x2  __attribute__((ext_vector_type(2)));
typedef u32   u32x4  __attribute__((ext_vector_type(4)));
typedef short s16x8  __attribute__((ext_vector_type(8)));   // MFMA bf16 A/B frag
typedef float f32x4  __attribute__((ext_vector_type(4)));   // MFMA C/D frag

__device__ __forceinline__ float b2f(u16 u) {
    union { unsigned int i; float f; } x; x.i = ((unsigned int)u) << 16; return x.f;
}
__device__ __forceinline__ u16 f2b(float f) {   // round-to-nearest-even
    unsigned int u = __float_as_uint(f);
    return (u16)((u + 0x7FFF + ((u >> 16) & 1)) >> 16);
}
__device__ __forceinline__ float ex2(float x) {
    float r; asm("v_exp_f32 %0, %1" : "=v"(r) : "v"(x)); return r;
}
__device__ __forceinline__ u32 cvtpk(float lo, float hi) {  // bf16(lo)|bf16(hi)<<16
    u32 r; asm("v_cvt_pk_bf16_f32 %0, %1, %2" : "=v"(r) : "v"(lo), "v"(hi)); return r;
}
__device__ __forceinline__ void gload16(const u16* g, u16* l) {
    __builtin_amdgcn_global_load_lds(
        (const __attribute__((address_space(1))) void*)g,
        (__attribute__((address_space(3))) void*)l, 16, 0, 0);
}
// 8 transpose-reads covering one 4KB region: index = K32*2 + hi
__device__ __forceinline__ void tr8(u32 a, u16x4 t[8]) {
    asm volatile("ds_read_b64_tr_b16 %0, %1"             : "=v"(t[0]) : "v"(a));
    asm volatile("ds_read_b64_tr_b16 %0, %1 offset:512"  : "=v"(t[1]) : "v"(a));
    asm volatile("ds_read_b64_tr_b16 %0, %1 offset:1024" : "=v"(t[2]) : "v"(a));
    asm volatile("ds_read_b64_tr_b16 %0, %1 offset:1536" : "=v"(t[3]) : "v"(a));
    asm volatile("ds_read_b64_tr_b16 %0, %1 offset:2048" : "=v"(t[4]) : "v"(a));
    asm volatile("ds_read_b64_tr_b16 %0, %1 offset:2560" : "=v"(t[5]) : "v"(a));
    asm volatile("ds_read_b64_tr_b16 %0, %1 offset:3072" : "=v"(t[6]) : "v"(a));
    asm volatile("ds_read_b64_tr_b16 %0, %1 offset:3584" : "=v"(t[7]) : "v"(a));
}
#define LGKM0_FENCE() do { \
    asm volatile("s_waitcnt lgkmcnt(0)" ::: "memory"); \
    __builtin_amdgcn_sched_barrier(0); } while (0)

// ---------------------------------------------------------------------------
// transpose + convert: in [K][N] f32 -> out [N][K] bf16 (32x32 LDS tiles)
// ---------------------------------------------------------------------------
__global__ __launch_bounds__(256)
void transpose_conv(const float* __restrict__ in, u16* __restrict__ out, int K, int N)
{
    __shared__ float tile[32][33];
    const int n0 = blockIdx.x * 32, k0 = blockIdx.y * 32;
    const int tx = threadIdx.x & 31, ty = threadIdx.x >> 5;
#pragma unroll
    for (int j = 0; j < 4; ++j)
        tile[ty + j * 8][tx] = in[(size_t)(k0 + ty + j * 8) * N + n0 + tx];
    __syncthreads();
#pragma unroll
    for (int j = 0; j < 4; ++j)
        out[(size_t)(n0 + ty + j * 8) * K + k0 + tx] = f2b(tile[tx][ty + j * 8]);
}

// ---------------------------------------------------------------------------
// bf16 MFMA GEMM, m97 structure + XCD swizzle. C = A @ B + bias, B transposed
// (Bt[N][K] bf16). A is fp32 (fused convert, reg-staged) or bf16 (gload_lds).
// 128x128 tile, BK=64, 4 waves (2x2).
// ---------------------------------------------------------------------------
template<typename AT, typename OutT>
__global__ __launch_bounds__(256)
void gemm_bf16(const AT* __restrict__ A, const u16* __restrict__ Bt,
               const float* __restrict__ bias, OutT* __restrict__ C,
               int M, int N, int K)
{
    __shared__ u16 As[128 * 64];
    __shared__ u16 Bs[128 * 64];

    const int tid  = threadIdx.x;
    const int lane = tid & 63;
    const int wid  = tid >> 6;
    const int wr   = wid >> 1;
    const int wc   = wid & 1;
    const int g    = lane >> 4;
    const int rr   = lane & 15;
    const int srow = lane >> 3;
    const int sslt = lane & 7;

    // XCD-aware bijective swizzle (grid % 8 == 0 for all our launches)
    const int nwg = (int)(gridDim.x * gridDim.y);
    int fid = (int)(blockIdx.y * gridDim.x + blockIdx.x);
    fid = (fid & 7) * (nwg >> 3) + (fid >> 3);
    const int n0 = (fid % (int)gridDim.x) * 128;
    const int m0 = (fid / (int)gridDim.x) * 128;

    f32x4 acc[4][4];
#pragma unroll
    for (int m = 0; m < 4; ++m)
#pragma unroll
        for (int n = 0; n < 4; ++n) acc[m][n] = (f32x4){0.f, 0.f, 0.f, 0.f};

    for (int k0 = 0; k0 < K; k0 += 64) {
        float4 a0[4], a1[4];
        if constexpr (sizeof(AT) == 4) {       // issue A loads before the barrier
#pragma unroll
            for (int p = 0; p < 4; ++p) {
                const int r = (p * 4 + wid) * 8 + srow;
                const float* ap = (const float*)A + (size_t)(m0 + r) * K + k0 + sslt * 8;
                a0[p] = *reinterpret_cast<const float4*>(ap);
                a1[p] = *reinterpret_cast<const float4*>(ap + 4);
            }
        }
        __syncthreads();                       // prev tile's compute done
#pragma unroll
        for (int p = 0; p < 4; ++p) {
            const int q = p * 4 + wid;
            const int r = q * 8 + srow;
            gload16(Bt + (size_t)(n0 + r) * K + k0 + sslt * 8, &Bs[q * 512]);
            if constexpr (sizeof(AT) == 2)
                gload16((const u16*)A + (size_t)(m0 + r) * K + k0 + sslt * 8, &As[q * 512]);
        }
        if constexpr (sizeof(AT) == 4) {
#pragma unroll
            for (int p = 0; p < 4; ++p) {
                const int q = p * 4 + wid;
                u32x4 w;
                w[0] = cvtpk(a0[p].x, a0[p].y); w[1] = cvtpk(a0[p].z, a0[p].w);
                w[2] = cvtpk(a1[p].x, a1[p].y); w[3] = cvtpk(a1[p].z, a1[p].w);
                *reinterpret_cast<u32x4*>(&As[q * 512 + lane * 8]) = w;
            }
        }
        __syncthreads();                       // drains vmcnt+lgkm before barrier

#pragma unroll
        for (int kk = 0; kk < 2; ++kk) {
            s16x8 af[4], bfr[4];
            const int s = kk * 4 + g;
#pragma unroll
            for (int m = 0; m < 4; ++m)
                af[m] = *reinterpret_cast<const s16x8*>(
                    &As[(wr * 64 + m * 16 + rr) * 64 + s * 8]);
#pragma unroll
            for (int n = 0; n < 4; ++n)
                bfr[n] = *reinterpret_cast<const s16x8*>(
                    &Bs[(wc * 64 + n * 16 + rr) * 64 + s * 8]);
#pragma unroll
            for (int m = 0; m < 4; ++m)
#pragma unroll
                for (int n = 0; n < 4; ++n)
                    acc[m][n] = __builtin_amdgcn_mfma_f32_16x16x32_bf16(
                        af[m], bfr[n], acc[m][n], 0, 0, 0);
        }
    }

    // C/D map: col=lane&15, row=(lane>>4)*4+j
#pragma unroll
    for (int m = 0; m < 4; ++m) {
#pragma unroll
        for (int n = 0; n < 4; ++n) {
            const int col = n0 + wc * 64 + n * 16 + rr;
            const float bv = bias[col];
#pragma unroll
            for (int j = 0; j < 4; ++j) {
                const int row = m0 + wr * 64 + m * 16 + g * 4 + j;
                const float v = acc[m][n][j] + bv;
                if constexpr (sizeof(OutT) == 2)
                    C[(size_t)row * N + col] = (OutT)f2b(v);
                else
                    C[(size_t)row * N + col] = (OutT)v;
            }
        }
    }
}

// ---------------------------------------------------------------------------
// MFMA causal flash attention, KVBLK=128, slot-layout V (b128 stores + tr-read
// B-frags), software-pipelined KV loads, paired q-tiles (y, 15-y): 17 uniform
// kt-iterations per block. 4 waves x 32 q-rows of one (b,h).
// ---------------------------------------------------------------------------
__global__ __launch_bounds__(256)
void attn_mfma(const u16* __restrict__ qkv, u16* __restrict__ out)
{
    __shared__ __align__(128) u16 Ks[128 * 64];   // 16 KB row-major swizzled
    __shared__ __align__(128) u16 Vl[4 * 2048];   // 16 KB slot layout, dn regions
    __shared__ __align__(128) u16 Pl[4 * 4096];   // 32 KB (8 KB per wave)

    const int tid  = threadIdx.x;
    const int lane = tid & 63;
    const int wid  = tid >> 6;
    const int c    = lane & 15;
    const int g    = lane >> 4;

    const int bh = blockIdx.x;
    const int b  = bh >> 4;
    const int h  = bh & 15;

    const int skey = tid >> 3;        // 0..31 staging key
    const int sb   = tid & 7;         // 16B d-block
    const int kswz = (sb ^ (skey & 7)) * 8;
    const int vslotb = ((skey >> 2) & 1) * 16 + (((skey >> 4) & 1) * 2 + ((skey >> 3) & 1)) * 4
                     + (skey & 3);
    const int vaddr0 = (sb >> 1) * 2048 + vslotb * 16 + (sb & 1) * 8;   // u16 idx
    const int slotc  = ((c >> 2) & 1) * 16 + (c >> 3) * 4 + (c & 3);    // P slot base

    const u32 pbyte = ((u32)(size_t)(&Pl[0])) + wid * 8192 + lane * 8;
    const u32 vbyte = ((u32)(size_t)(&Vl[0])) + lane * 8;
    const float QSC = 0.18033688f;    // 0.125 * log2(e)

    u16x8 kreg[4], vreg[4];
    const u16* kvbase = qkv + (size_t)b * Tsz * (3 * Csz) + Csz + h * HD + sb * 8;
    auto load_kv = [&](int kt) {
#pragma unroll
        for (int p = 0; p < 4; ++p) {
            const u16* gk = kvbase + (size_t)(kt + skey + p * 32) * (3 * Csz);
            kreg[p] = *reinterpret_cast<const u16x8*>(gk);
            vreg[p] = *reinterpret_cast<const u16x8*>(gk + Csz);
        }
    };

    for (int half = 0; half < 2; ++half) {
        const int yt  = half ? 15 - (int)blockIdx.y : (int)blockIdx.y;
        const int t0  = yt * 128;
        const int qb0 = t0 + wid * 32;

        // Q fragments, pre-scaled by QSC
        s16x8 qf[2][2];
#pragma unroll
        for (int m = 0; m < 2; ++m)
#pragma unroll
            for (int kk = 0; kk < 2; ++kk) {
                u16x8 raw = *reinterpret_cast<const u16x8*>(
                    qkv + (size_t)(b * Tsz + qb0 + m * 16 + c) * (3 * Csz)
                        + h * HD + kk * 32 + g * 8);
                s16x8 qv;
#pragma unroll
                for (int i = 0; i < 8; ++i) qv[i] = (short)f2b(b2f(raw[i]) * QSC);
                qf[m][kk] = qv;
            }

        f32x4 acco[2][4];
#pragma unroll
        for (int m = 0; m < 2; ++m)
#pragma unroll
            for (int dn = 0; dn < 4; ++dn) acco[m][dn] = (f32x4){0.f, 0.f, 0.f, 0.f};
        float mrun[8], lrun[8];
#pragma unroll
        for (int i = 0; i < 8; ++i) { mrun[i] = -1e30f; lrun[i] = 0.f; }

        load_kv(0);   // prologue

        for (int kt = 0; kt < t0 + 128; kt += 128) {
            __syncthreads();           // LDS free
            // ---- stage K + V from regs ----
#pragma unroll
            for (int p = 0; p < 4; ++p) {
                *reinterpret_cast<u16x8*>(&Ks[(skey + p * 32) * 64 + kswz]) = kreg[p];
                *reinterpret_cast<u16x8*>(&Vl[vaddr0 + p * 512]) = vreg[p];
            }
            if (kt < t0) load_kv(kt + 128);   // pipeline next tile's loads
            __syncthreads();

            {
                // ---- S' = (Q*QSC) K^T ----
                f32x4 accS[2][8];
#pragma unroll
                for (int m = 0; m < 2; ++m)
#pragma unroll
                    for (int n = 0; n < 8; ++n) accS[m][n] = (f32x4){0.f, 0.f, 0.f, 0.f};
#pragma unroll
                for (int kk = 0; kk < 2; ++kk)
#pragma unroll
                    for (int nh = 0; nh < 2; ++nh) {
                        s16x8 kf[4];
#pragma unroll
                        for (int i = 0; i < 4; ++i) {
                            const int key = (nh * 4 + i) * 16 + c;
                            kf[i] = *reinterpret_cast<const s16x8*>(
                                &Ks[key * 64 + (((kk * 4 + g) ^ (c & 7)) * 8)]);
                        }
#pragma unroll
                        for (int m = 0; m < 2; ++m)
#pragma unroll
                            for (int i = 0; i < 4; ++i)
                                accS[m][nh * 4 + i] = __builtin_amdgcn_mfma_f32_16x16x32_bf16(
                                    qf[m][kk], kf[i], accS[m][nh * 4 + i], 0, 0, 0);
                    }

                // ---- causal mask (diagonal iteration only) ----
                if (kt == t0) {
#pragma unroll
                    for (int m = 0; m < 2; ++m)
#pragma unroll
                        for (int n = 0; n < 8; ++n) {
                            const int kgl = kt + n * 16 + c;
#pragma unroll
                            for (int j = 0; j < 4; ++j)
                                if (kgl > qb0 + m * 16 + g * 4 + j) accS[m][n][j] = -1e30f;
                        }
                }

                // ---- row max ----
                float pm[8];
#pragma unroll
                for (int m = 0; m < 2; ++m)
#pragma unroll
                    for (int j = 0; j < 4; ++j) {
                        float v = accS[m][0][j];
#pragma unroll
                        for (int n = 1; n < 8; ++n) v = fmaxf(v, accS[m][n][j]);
                        pm[m * 4 + j] = v;
                    }
#pragma unroll
                for (int msk = 1; msk < 16; msk <<= 1)
#pragma unroll
                    for (int i = 0; i < 8; ++i)
                        pm[i] = fmaxf(pm[i], __shfl_xor(pm[i], msk));

                // ---- defer-max (T13): rescale only if max grew > 8 (log2) ----
                int need = 0;
#pragma unroll
                for (int i = 0; i < 8; ++i) need |= (pm[i] > mrun[i] + 8.f);
                if (__any(need)) {
                    float cv[8];
#pragma unroll
                    for (int i = 0; i < 8; ++i) {
                        const float mn = fmaxf(mrun[i], pm[i]);
                        cv[i] = ex2(mrun[i] - mn);
                        mrun[i] = mn;
                        lrun[i] *= cv[i];
                    }
#pragma unroll
                    for (int m = 0; m < 2; ++m)
#pragma unroll
                        for (int dn = 0; dn < 4; ++dn)
#pragma unroll
                            for (int j = 0; j < 4; ++j)
                                acco[m][dn][j] *= cv[m * 4 + j];
                }

                // ---- P = 2^(S'-m'); pack; store in tr-slot layout ----
#pragma unroll
                for (int m = 0; m < 2; ++m)
#pragma unroll
                    for (int n = 0; n < 8; ++n) {
                        float pv[4];
#pragma unroll
                        for (int j = 0; j < 4; ++j) {
                            pv[j] = ex2(accS[m][n][j] - mrun[m * 4 + j]);
                            lrun[m * 4 + j] += pv[j];
                        }
                        const int slot = (n >> 1) * 32 + (n & 1) * 8 + slotc;
                        *reinterpret_cast<u32x2*>(
                            &Pl[wid * 4096 + m * 2048 + slot * 16 + g * 4]) =
                            (u32x2){cvtpk(pv[0], pv[1]), cvtpk(pv[2], pv[3])};
                    }
                LGKM0_FENCE();

                // ---- P A-frags via tr-read ----
                u16x4 tp0[8], tp1[8];
                tr8(pbyte, tp0);
                tr8(pbyte + 4096, tp1);
                LGKM0_FENCE();
                s16x8 pa[2][4];
#pragma unroll
                for (int K32 = 0; K32 < 4; ++K32)
#pragma unroll
                    for (int q = 0; q < 4; ++q) {
                        pa[0][K32][q] = (short)tp0[K32 * 2][q];
                        pa[0][K32][q + 4] = (short)tp0[K32 * 2 + 1][q];
                        pa[1][K32][q] = (short)tp1[K32 * 2][q];
                        pa[1][K32][q + 4] = (short)tp1[K32 * 2 + 1][q];
                    }

                // ---- O += P V  (V B-frags via tr-read per dn region) ----
#pragma unroll
                for (int dn = 0; dn < 4; ++dn) {
                    u16x4 tv[8];
                    tr8(vbyte + dn * 4096, tv);
                    LGKM0_FENCE();
                    s16x8 vfk[4];
#pragma unroll
                    for (int K32 = 0; K32 < 4; ++K32)
#pragma unroll
                        for (int q = 0; q < 4; ++q) {
                            vfk[K32][q] = (short)tv[K32 * 2][q];
                            vfk[K32][q + 4] = (short)tv[K32 * 2 + 1][q];
                        }
#pragma unroll
                    for (int m = 0; m < 2; ++m)
#pragma unroll
                        for (int K32 = 0; K32 < 4; ++K32)
                            acco[m][dn] = __builtin_amdgcn_mfma_f32_16x16x32_bf16(
                                pa[m][K32], vfk[K32], acco[m][dn], 0, 0, 0);
                }
            }
        }

        // ---- finalize this q-tile ----
#pragma unroll
        for (int msk = 1; msk < 16; msk <<= 1)
#pragma unroll
            for (int i = 0; i < 8; ++i)
                lrun[i] += __shfl_xor(lrun[i], msk);
        float inv[8];
#pragma unroll
        for (int i = 0; i < 8; ++i) inv[i] = 1.f / lrun[i];
#pragma unroll
        for (int m = 0; m < 2; ++m)
#pragma unroll
            for (int dn = 0; dn < 4; ++dn)
#pragma unroll
                for (int j = 0; j < 4; ++j) {
                    const int q = qb0 + m * 16 + g * 4 + j;
                    out[(size_t)(b * Tsz + q) * Csz + h * HD + dn * 16 + c] =
                        f2b(acco[m][dn][j] * inv[m * 4 + j]);
                }
        __syncthreads();   // protect LDS before next half restages
    }
}

// ---------------------------------------------------------------------------
extern "C" void kernel_launch(void* const* d_in, const int* in_sizes, int n_in,
                              void* d_out, int out_size, void* d_ws, size_t ws_size,
                              hipStream_t stream) {
    const float* x      = (const float*)d_in[0];   // [B,T,C]
    const float* w_attn = (const float*)d_in[1];   // [C,3C]
    const float* b_attn = (const float*)d_in[2];   // [3C]
    const float* w_proj = (const float*)d_in[3];   // [C,C]
    const float* b_proj = (const float*)d_in[4];   // [C]
    float* out = (float*)d_out;                    // [B,T,C] fp32

    // ws: qkv_bf 48M | ao_bf 16M | wat 6M | wpt 2M
    char* w = (char*)d_ws;
    u16* qkv_bf = (u16*)w;  w += (size_t)NT * 3 * Csz * 2;
    u16* ao_bf  = (u16*)w;  w += (size_t)NT * Csz * 2;
    u16* wat    = (u16*)w;  w += (size_t)3 * Csz * Csz * 2;
    u16* wpt    = (u16*)w;

    transpose_conv<<<dim3(3 * Csz / 32, Csz / 32), 256, 0, stream>>>(w_attn, wat, Csz, 3 * Csz);
    transpose_conv<<<dim3(Csz / 32, Csz / 32), 256, 0, stream>>>(w_proj, wpt, Csz, Csz);

    // qkv = x @ w_attn + b_attn  (fused fp32->bf16 on A)
    gemm_bf16<float, u16><<<dim3(3 * Csz / 128, NT / 128), 256, 0, stream>>>(
        x, wat, b_attn, qkv_bf, NT, 3 * Csz, Csz);

    attn_mfma<<<dim3(Bsz * NH, 8), 256, 0, stream>>>(qkv_bf, ao_bf);

    gemm_bf16<u16, float><<<dim3(Csz / 128, NT / 128), 256, 0, stream>>>(
        ao_bf, wpt, b_proj, out, NT, Csz, Csz);
}

// Round 7
// 316.088 us; speedup vs baseline: 1.0186x; 1.0186x over previous
//
#include <hip/hip_runtime.h>
#include <hip/hip_bf16.h>

// Problem: B=4, T=2048, C=1024, H=16, D=64
#define Bsz 4
#define Tsz 2048
#define Csz 1024
#define NH  16
#define HD  64
#define NT  (Bsz * Tsz)          // 8192 rows

typedef unsigned short u16;
typedef unsigned int   u32;
typedef u16   u16x8  __attribute__((ext_vector_type(8)));
typedef u16   u16x4  __attribute__((ext_vector_type(4)));
typedef u32   u32x2  __attribute__((ext_vector_type(2)));
typedef short s16x8  __attribute__((ext_vector_type(8)));   // MFMA bf16 A/B frag
typedef float f32x4  __attribute__((ext_vector_type(4)));   // MFMA C/D frag

__device__ __forceinline__ float b2f(u16 u) {
    union { unsigned int i; float f; } x; x.i = ((unsigned int)u) << 16; return x.f;
}
__device__ __forceinline__ u16 f2b(float f) {   // round-to-nearest-even
    unsigned int u = __float_as_uint(f);
    return (u16)((u + 0x7FFF + ((u >> 16) & 1)) >> 16);
}
__device__ __forceinline__ float ex2(float x) {
    float r; asm("v_exp_f32 %0, %1" : "=v"(r) : "v"(x)); return r;
}
__device__ __forceinline__ u32 cvtpk(float lo, float hi) {  // bf16(lo)|bf16(hi)<<16
    u32 r; asm("v_cvt_pk_bf16_f32 %0, %1, %2" : "=v"(r) : "v"(lo), "v"(hi)); return r;
}
__device__ __forceinline__ void gload16(const u16* g, u16* l) {
    __builtin_amdgcn_global_load_lds(
        (const __attribute__((address_space(1))) void*)g,
        (__attribute__((address_space(3))) void*)l, 16, 0, 0);
}
// 4 transpose-reads covering one 2KB wave region: index = kk*2 + hi
__device__ __forceinline__ void tr4(u32 a, u16x4 t[4]) {
    asm volatile("ds_read_b64_tr_b16 %0, %1"             : "=v"(t[0]) : "v"(a));
    asm volatile("ds_read_b64_tr_b16 %0, %1 offset:512"  : "=v"(t[1]) : "v"(a));
    asm volatile("ds_read_b64_tr_b16 %0, %1 offset:1024" : "=v"(t[2]) : "v"(a));
    asm volatile("ds_read_b64_tr_b16 %0, %1 offset:1536" : "=v"(t[3]) : "v"(a));
}
#define LGKM0_FENCE() do { \
    asm volatile("s_waitcnt lgkmcnt(0)" ::: "memory"); \
    __builtin_amdgcn_sched_barrier(0); } while (0)

// ---------------------------------------------------------------------------
// fp32 -> bf16 bulk convert (8 elems/thread)
// ---------------------------------------------------------------------------
__global__ __launch_bounds__(256)
void conv_f32_bf16(const float* __restrict__ in, u16* __restrict__ out, int n8)
{
    int t = blockIdx.x * 256 + threadIdx.x;
    if (t >= n8) return;
    const float4* p = reinterpret_cast<const float4*>(in) + (size_t)t * 2;
    float4 a = p[0], b = p[1];
    u16x8 w;
    w[0] = f2b(a.x); w[1] = f2b(a.y); w[2] = f2b(a.z); w[3] = f2b(a.w);
    w[4] = f2b(b.x); w[5] = f2b(b.y); w[6] = f2b(b.z); w[7] = f2b(b.w);
    *(reinterpret_cast<u16x8*>(out) + t) = w;
}

// ---------------------------------------------------------------------------
// transpose + convert: in [K][N] f32 -> out [N][K] bf16 (32x32 LDS tiles)
// ---------------------------------------------------------------------------
__global__ __launch_bounds__(256)
void transpose_conv(const float* __restrict__ in, u16* __restrict__ out, int K, int N)
{
    __shared__ float tile[32][33];
    const int n0 = blockIdx.x * 32, k0 = blockIdx.y * 32;
    const int tx = threadIdx.x & 31, ty = threadIdx.x >> 5;
#pragma unroll
    for (int j = 0; j < 4; ++j)
        tile[ty + j * 8][tx] = in[(size_t)(k0 + ty + j * 8) * N + n0 + tx];
    __syncthreads();
#pragma unroll
    for (int j = 0; j < 4; ++j)
        out[(size_t)(n0 + ty + j * 8) * K + k0 + tx] = f2b(tile[tx][ty + j * 8]);
}

// ---------------------------------------------------------------------------
// bf16 MFMA GEMM (round-4 verified config): global_load_lds(16B) staging into
// LINEAR LDS, 2-barrier K-loop. C = A @ B + bias, B transposed (Bt[N][K]).
// 128x128 tile, BK=64, 4 waves (2x2).
// ---------------------------------------------------------------------------
template<typename OutT>
__global__ __launch_bounds__(256)
void gemm_bf16(const u16* __restrict__ A, const u16* __restrict__ Bt,
               const float* __restrict__ bias, OutT* __restrict__ C,
               int M, int N, int K)
{
    __shared__ u16 As[128 * 64];   // 16 KB, linear [row][64]
    __shared__ u16 Bs[128 * 64];   // 16 KB, rows = output cols

    const int tid  = threadIdx.x;
    const int lane = tid & 63;
    const int wid  = tid >> 6;
    const int wr   = wid >> 1;
    const int wc   = wid & 1;
    const int g    = lane >> 4;
    const int rr   = lane & 15;
    const int srow = lane >> 3;      // staging: row-within-chunk 0..7
    const int sslt = lane & 7;       // staging: 16B slot 0..7

    const int n0 = blockIdx.x * 128;
    const int m0 = blockIdx.y * 128;

    f32x4 acc[4][4];
#pragma unroll
    for (int m = 0; m < 4; ++m)
#pragma unroll
        for (int n = 0; n < 4; ++n) acc[m][n] = (f32x4){0.f, 0.f, 0.f, 0.f};

    for (int k0 = 0; k0 < K; k0 += 64) {
        __syncthreads();             // prev tile's compute done
#pragma unroll
        for (int p = 0; p < 4; ++p) {
            const int q = p * 4 + wid;          // chunk 0..15 (8 rows each)
            const int r = q * 8 + srow;
            gload16(A  + (size_t)(m0 + r) * K + k0 + sslt * 8, &As[q * 512]);
            gload16(Bt + (size_t)(n0 + r) * K + k0 + sslt * 8, &Bs[q * 512]);
        }
        __syncthreads();             // compiler drains vmcnt before barrier

#pragma unroll
        for (int kk = 0; kk < 2; ++kk) {
            s16x8 af[4], bfr[4];
            const int s = kk * 4 + g;
#pragma unroll
            for (int m = 0; m < 4; ++m)
                af[m] = *reinterpret_cast<const s16x8*>(
                    &As[(wr * 64 + m * 16 + rr) * 64 + s * 8]);
#pragma unroll
            for (int n = 0; n < 4; ++n)
                bfr[n] = *reinterpret_cast<const s16x8*>(
                    &Bs[(wc * 64 + n * 16 + rr) * 64 + s * 8]);
#pragma unroll
            for (int m = 0; m < 4; ++m)
#pragma unroll
                for (int n = 0; n < 4; ++n)
                    acc[m][n] = __builtin_amdgcn_mfma_f32_16x16x32_bf16(
                        af[m], bfr[n], acc[m][n], 0, 0, 0);
        }
    }

    // C/D map: col=lane&15, row=(lane>>4)*4+j
#pragma unroll
    for (int m = 0; m < 4; ++m) {
#pragma unroll
        for (int n = 0; n < 4; ++n) {
            const int col = n0 + wc * 64 + n * 16 + rr;
            const float bv = bias[col];
#pragma unroll
            for (int j = 0; j < 4; ++j) {
                const int row = m0 + wr * 64 + m * 16 + g * 4 + j;
                const float v = acc[m][n][j] + bv;
                if constexpr (sizeof(OutT) == 2)
                    C[(size_t)row * N + col] = (OutT)f2b(v);
                else
                    C[(size_t)row * N + col] = (OutT)v;
            }
        }
    }
}

// ---------------------------------------------------------------------------
// MFMA causal flash attention, occupancy-first layout.
// QBLK=64 (4 waves x 16 q-rows), KVBLK=64. Grid (64 bh, 16): block y handles
// q-subtiles y and 31-y -> uniform 33 kt-iters. 1024 blocks = 4 blocks/CU all
// resident (LDS 24 KB, ~16 waves/CU). Zero wave divergence: every wave active
// every iteration; causal mask only on the kt==t0 diagonal tile.
// All index algebra is the round-4-verified mapping with the m dim dropped.
// ---------------------------------------------------------------------------
__global__ __launch_bounds__(256)
void attn_mfma(const u16* __restrict__ qkv, u16* __restrict__ out)
{
    __shared__ __align__(128) u16 Ks[64 * 64];    // 8 KB, row-major swizzled
    __shared__ __align__(128) u16 Vt[64 * 64];    // 8 KB, transposed swizzled
    __shared__ __align__(128) u16 Pl[4 * 1024];   // 8 KB (2 KB per wave)

    const int tid  = threadIdx.x;
    const int lane = tid & 63;
    const int wid  = tid >> 6;
    const int c    = lane & 15;       // key-col within fragment
    const int g    = lane >> 4;       // k-group / row-quad select

    const int bh = blockIdx.x;        // 0..63
    const int b  = bh >> 4;
    const int h  = bh & 15;

    const int skey = tid >> 3;        // staging key 0..31 (+32 second pass)
    const int sb   = tid & 7;         // staging 16B d-block
    const int kswz = (sb ^ (skey & 7)) * 8;
    const int slotc = ((c >> 2) & 1) * 16 + (c >> 3) * 4 + (c & 3);  // P slot base
    const u32 pbyte = ((u32)(size_t)(&Pl[0])) + wid * 2048 + lane * 8;
    const float QSC = 0.18033688f;    // 0.125 * log2(e)

    for (int half = 0; half < 2; ++half) {
        const int yt  = half ? 31 - (int)blockIdx.y : (int)blockIdx.y;
        const int t0  = yt * 64;
        const int qb0 = t0 + wid * 16;     // this wave's 16 q-rows

        // ---- Q fragments, pre-scaled by QSC ----
        s16x8 qf[2];
#pragma unroll
        for (int kk = 0; kk < 2; ++kk) {
            u16x8 raw = *reinterpret_cast<const u16x8*>(
                qkv + (size_t)(b * Tsz + qb0 + c) * (3 * Csz) + h * HD + kk * 32 + g * 8);
            s16x8 qv;
#pragma unroll
            for (int i = 0; i < 8; ++i) qv[i] = (short)f2b(b2f(raw[i]) * QSC);
            qf[kk] = qv;
        }

        f32x4 acco[4];
#pragma unroll
        for (int dn = 0; dn < 4; ++dn) acco[dn] = (f32x4){0.f, 0.f, 0.f, 0.f};
        float mrun[4], lrun[4];
#pragma unroll
        for (int i = 0; i < 4; ++i) { mrun[i] = -1e30f; lrun[i] = 0.f; }

        for (int kt = 0; kt <= t0; kt += 64) {
            __syncthreads();           // prev compute / prev half done
            // ---- stage K (swizzled b128) + V (transposed scatter) ----
#pragma unroll
            for (int p = 0; p < 2; ++p) {
                const int key = skey + p * 32;
                const u16* gk = qkv + (size_t)(b * Tsz + kt + key) * (3 * Csz)
                                + Csz + h * HD + sb * 8;
                u16x8 kv = *reinterpret_cast<const u16x8*>(gk);
                u16x8 vv = *reinterpret_cast<const u16x8*>(gk + Csz);
                *reinterpret_cast<u16x8*>(&Ks[key * 64 + kswz]) = kv;
#pragma unroll
                for (int i = 0; i < 8; ++i) {
                    const int d = sb * 8 + i;               // swz(d) = i^sb
                    Vt[d * 64 + (key ^ (((i ^ sb) & 7) << 3))] = vv[i];
                }
            }
            __syncthreads();

            // ---- S' = (Q*QSC) K^T ----
            f32x4 accS[4];
#pragma unroll
            for (int n = 0; n < 4; ++n) accS[n] = (f32x4){0.f, 0.f, 0.f, 0.f};
            __builtin_amdgcn_s_setprio(1);
#pragma unroll
            for (int kk = 0; kk < 2; ++kk) {
                s16x8 kf[4];
#pragma unroll
                for (int n = 0; n < 4; ++n) {
                    const int key = n * 16 + c;
                    kf[n] = *reinterpret_cast<const s16x8*>(
                        &Ks[key * 64 + (((kk * 4 + g) ^ (c & 7)) * 8)]);
                }
#pragma unroll
                for (int n = 0; n < 4; ++n)
                    accS[n] = __builtin_amdgcn_mfma_f32_16x16x32_bf16(
                        qf[kk], kf[n], accS[n], 0, 0, 0);
            }
            __builtin_amdgcn_s_setprio(0);

            // ---- causal mask (diagonal tile only) ----
            if (kt == t0) {
#pragma unroll
                for (int n = 0; n < 4; ++n) {
                    const int kgl = kt + n * 16 + c;
#pragma unroll
                    for (int j = 0; j < 4; ++j)
                        if (kgl > qb0 + g * 4 + j) accS[n][j] = -1e30f;
                }
            }

            // ---- row max (across the 16 c-lanes) ----
            float pm[4];
#pragma unroll
            for (int j = 0; j < 4; ++j)
                pm[j] = fmaxf(fmaxf(accS[0][j], accS[1][j]),
                              fmaxf(accS[2][j], accS[3][j]));
#pragma unroll
            for (int msk = 1; msk < 16; msk <<= 1)
#pragma unroll
                for (int i = 0; i < 4; ++i)
                    pm[i] = fmaxf(pm[i], __shfl_xor(pm[i], msk));

            // ---- defer-max (T13): rescale only if max grew > 8 (log2) ----
            int need = 0;
#pragma unroll
            for (int i = 0; i < 4; ++i) need |= (pm[i] > mrun[i] + 8.f);
            if (__any(need)) {
                float cv[4];
#pragma unroll
                for (int i = 0; i < 4; ++i) {
                    const float mn = fmaxf(mrun[i], pm[i]);
                    cv[i] = ex2(mrun[i] - mn);
                    mrun[i] = mn;
                    lrun[i] *= cv[i];
                }
#pragma unroll
                for (int dn = 0; dn < 4; ++dn)
#pragma unroll
                    for (int j = 0; j < 4; ++j)
                        acco[dn][j] *= cv[j];
            }

            // ---- P = 2^(S'-m'); pack; store in tr-slot layout ----
#pragma unroll
            for (int n = 0; n < 4; ++n) {
                float pv[4];
#pragma unroll
                for (int j = 0; j < 4; ++j) {
                    pv[j] = ex2(accS[n][j] - mrun[j]);
                    lrun[j] += pv[j];
                }
                const int slot = (n >> 1) * 32 + (n & 1) * 8 + slotc;
                *reinterpret_cast<u32x2*>(&Pl[wid * 1024 + slot * 16 + g * 4]) =
                    (u32x2){cvtpk(pv[0], pv[1]), cvtpk(pv[2], pv[3])};
            }
            LGKM0_FENCE();

            // ---- P A-frags via hardware transpose read ----
            u16x4 tp[4];
            tr4(pbyte, tp);
            LGKM0_FENCE();
            s16x8 pa[2];
#pragma unroll
            for (int kk = 0; kk < 2; ++kk)
#pragma unroll
                for (int q = 0; q < 4; ++q) {
                    pa[kk][q]     = (short)tp[kk * 2][q];
                    pa[kk][q + 4] = (short)tp[kk * 2 + 1][q];
                }

            // ---- O += P V ----
#pragma unroll
            for (int kk = 0; kk < 2; ++kk) {
                s16x8 vf[4];
#pragma unroll
                for (int dn = 0; dn < 4; ++dn) {
                    const int d = dn * 16 + c;
                    const int swz = (c & 7) ^ ((dn * 2 + (c >> 3)) & 7);
                    vf[dn] = *reinterpret_cast<const s16x8*>(
                        &Vt[d * 64 + (((kk * 4 + g) ^ swz) * 8)]);
                }
                __builtin_amdgcn_s_setprio(1);
#pragma unroll
                for (int dn = 0; dn < 4; ++dn)
                    acco[dn] = __builtin_amdgcn_mfma_f32_16x16x32_bf16(
                        pa[kk], vf[dn], acco[dn], 0, 0, 0);
                __builtin_amdgcn_s_setprio(0);
            }
        }

        // ---- finalize this q-subtile ----
#pragma unroll
        for (int msk = 1; msk < 16; msk <<= 1)
#pragma unroll
            for (int i = 0; i < 4; ++i)
                lrun[i] += __shfl_xor(lrun[i], msk);
        float inv[4];
#pragma unroll
        for (int i = 0; i < 4; ++i) inv[i] = 1.f / lrun[i];
#pragma unroll
        for (int dn = 0; dn < 4; ++dn)
#pragma unroll
            for (int j = 0; j < 4; ++j) {
                const int q = qb0 + g * 4 + j;
                out[(size_t)(b * Tsz + q) * Csz + h * HD + dn * 16 + c] =
                    f2b(acco[dn][j] * inv[j]);
            }
    }
}

// ---------------------------------------------------------------------------
extern "C" void kernel_launch(void* const* d_in, const int* in_sizes, int n_in,
                              void* d_out, int out_size, void* d_ws, size_t ws_size,
                              hipStream_t stream) {
    const float* x      = (const float*)d_in[0];   // [B,T,C]
    const float* w_attn = (const float*)d_in[1];   // [C,3C]
    const float* b_attn = (const float*)d_in[2];   // [3C]
    const float* w_proj = (const float*)d_in[3];   // [C,C]
    const float* b_proj = (const float*)d_in[4];   // [C]
    float* out = (float*)d_out;                    // [B,T,C] fp32

    // ws: qkv_bf 48M | x_bf 16M | ao_bf 16M | wat 6M | wpt 2M
    char* w = (char*)d_ws;
    u16* qkv_bf = (u16*)w;  w += (size_t)NT * 3 * Csz * 2;
    u16* x_bf   = (u16*)w;  w += (size_t)NT * Csz * 2;
    u16* ao_bf  = (u16*)w;  w += (size_t)NT * Csz * 2;
    u16* wat    = (u16*)w;  w += (size_t)3 * Csz * Csz * 2;
    u16* wpt    = (u16*)w;

    conv_f32_bf16<<<(NT * Csz / 8 + 255) / 256, 256, 0, stream>>>(x, x_bf, NT * Csz / 8);
    transpose_conv<<<dim3(3 * Csz / 32, Csz / 32), 256, 0, stream>>>(w_attn, wat, Csz, 3 * Csz);
    transpose_conv<<<dim3(Csz / 32, Csz / 32), 256, 0, stream>>>(w_proj, wpt, Csz, Csz);

    gemm_bf16<u16><<<dim3(3 * Csz / 128, NT / 128), 256, 0, stream>>>(
        x_bf, wat, b_attn, qkv_bf, NT, 3 * Csz, Csz);

    attn_mfma<<<dim3(Bsz * NH, 16), 256, 0, stream>>>(qkv_bf, ao_bf);

    gemm_bf16<float><<<dim3(Csz / 128, NT / 128), 256, 0, stream>>>(
        ao_bf, wpt, b_proj, out, NT, Csz, Csz);
}

// Round 8
// 273.555 us; speedup vs baseline: 1.1770x; 1.1555x over previous
//
#include <hip/hip_runtime.h>
#include <hip/hip_bf16.h>

// Problem: B=4, T=2048, C=1024, H=16, D=64
#define Bsz 4
#define Tsz 2048
#define Csz 1024
#define NH  16
#define HD  64
#define NT  (Bsz * Tsz)          // 8192 rows

typedef unsigned short u16;
typedef unsigned int   u32;
typedef u16   u16x8  __attribute__((ext_vector_type(8)));
typedef short s16x8  __attribute__((ext_vector_type(8)));   // MFMA bf16 A/B frag
typedef float f32x4  __attribute__((ext_vector_type(4)));   // MFMA C/D frag

__device__ __forceinline__ float b2f(u16 u) {
    union { unsigned int i; float f; } x; x.i = ((unsigned int)u) << 16; return x.f;
}
__device__ __forceinline__ u16 f2b(float f) {   // round-to-nearest-even
    unsigned int u = __float_as_uint(f);
    return (u16)((u + 0x7FFF + ((u >> 16) & 1)) >> 16);
}
__device__ __forceinline__ float ex2(float x) {
    float r; asm("v_exp_f32 %0, %1" : "=v"(r) : "v"(x)); return r;
}
__device__ __forceinline__ u32 cvtpk(float lo, float hi) {  // bf16(lo)|bf16(hi)<<16
    u32 r; asm("v_cvt_pk_bf16_f32 %0, %1, %2" : "=v"(r) : "v"(lo), "v"(hi)); return r;
}
__device__ __forceinline__ void gload16(const u16* g, u16* l) {
    __builtin_amdgcn_global_load_lds(
        (const __attribute__((address_space(1))) void*)g,
        (__attribute__((address_space(3))) void*)l, 16, 0, 0);
}

// ---------------------------------------------------------------------------
// fp32 -> bf16 bulk convert (8 elems/thread)
// ---------------------------------------------------------------------------
__global__ __launch_bounds__(256)
void conv_f32_bf16(const float* __restrict__ in, u16* __restrict__ out, int n8)
{
    int t = blockIdx.x * 256 + threadIdx.x;
    if (t >= n8) return;
    const float4* p = reinterpret_cast<const float4*>(in) + (size_t)t * 2;
    float4 a = p[0], b = p[1];
    u16x8 w;
    w[0] = f2b(a.x); w[1] = f2b(a.y); w[2] = f2b(a.z); w[3] = f2b(a.w);
    w[4] = f2b(b.x); w[5] = f2b(b.y); w[6] = f2b(b.z); w[7] = f2b(b.w);
    *(reinterpret_cast<u16x8*>(out) + t) = w;
}

// ---------------------------------------------------------------------------
// transpose + convert: in [K][N] f32 -> out [N][K] bf16 (32x32 LDS tiles)
// ---------------------------------------------------------------------------
__global__ __launch_bounds__(256)
void transpose_conv(const float* __restrict__ in, u16* __restrict__ out, int K, int N)
{
    __shared__ float tile[32][33];
    const int n0 = blockIdx.x * 32, k0 = blockIdx.y * 32;
    const int tx = threadIdx.x & 31, ty = threadIdx.x >> 5;
#pragma unroll
    for (int j = 0; j < 4; ++j)
        tile[ty + j * 8][tx] = in[(size_t)(k0 + ty + j * 8) * N + n0 + tx];
    __syncthreads();
#pragma unroll
    for (int j = 0; j < 4; ++j)
        out[(size_t)(n0 + ty + j * 8) * K + k0 + tx] = f2b(tile[tx][ty + j * 8]);
}

// ---------------------------------------------------------------------------
// bf16 MFMA GEMM (round-4 verified config): global_load_lds(16B) staging into
// LINEAR LDS, 2-barrier K-loop. C = A @ B + bias, B transposed (Bt[N][K]).
// 128x128 tile, BK=64, 4 waves (2x2).
// ---------------------------------------------------------------------------
template<typename OutT>
__global__ __launch_bounds__(256)
void gemm_bf16(const u16* __restrict__ A, const u16* __restrict__ Bt,
               const float* __restrict__ bias, OutT* __restrict__ C,
               int M, int N, int K)
{
    __shared__ u16 As[128 * 64];   // 16 KB, linear [row][64]
    __shared__ u16 Bs[128 * 64];   // 16 KB, rows = output cols

    const int tid  = threadIdx.x;
    const int lane = tid & 63;
    const int wid  = tid >> 6;
    const int wr   = wid >> 1;
    const int wc   = wid & 1;
    const int g    = lane >> 4;
    const int rr   = lane & 15;
    const int srow = lane >> 3;      // staging: row-within-chunk 0..7
    const int sslt = lane & 7;       // staging: 16B slot 0..7

    const int n0 = blockIdx.x * 128;
    const int m0 = blockIdx.y * 128;

    f32x4 acc[4][4];
#pragma unroll
    for (int m = 0; m < 4; ++m)
#pragma unroll
        for (int n = 0; n < 4; ++n) acc[m][n] = (f32x4){0.f, 0.f, 0.f, 0.f};

    for (int k0 = 0; k0 < K; k0 += 64) {
        __syncthreads();             // prev tile's compute done
#pragma unroll
        for (int p = 0; p < 4; ++p) {
            const int q = p * 4 + wid;          // chunk 0..15 (8 rows each)
            const int r = q * 8 + srow;
            gload16(A  + (size_t)(m0 + r) * K + k0 + sslt * 8, &As[q * 512]);
            gload16(Bt + (size_t)(n0 + r) * K + k0 + sslt * 8, &Bs[q * 512]);
        }
        __syncthreads();             // compiler drains vmcnt before barrier

#pragma unroll
        for (int kk = 0; kk < 2; ++kk) {
            s16x8 af[4], bfr[4];
            const int s = kk * 4 + g;
#pragma unroll
            for (int m = 0; m < 4; ++m)
                af[m] = *reinterpret_cast<const s16x8*>(
                    &As[(wr * 64 + m * 16 + rr) * 64 + s * 8]);
#pragma unroll
            for (int n = 0; n < 4; ++n)
                bfr[n] = *reinterpret_cast<const s16x8*>(
                    &Bs[(wc * 64 + n * 16 + rr) * 64 + s * 8]);
#pragma unroll
            for (int m = 0; m < 4; ++m)
#pragma unroll
                for (int n = 0; n < 4; ++n)
                    acc[m][n] = __builtin_amdgcn_mfma_f32_16x16x32_bf16(
                        af[m], bfr[n], acc[m][n], 0, 0, 0);
        }
    }

    // C/D map: col=lane&15, row=(lane>>4)*4+j
#pragma unroll
    for (int m = 0; m < 4; ++m) {
#pragma unroll
        for (int n = 0; n < 4; ++n) {
            const int col = n0 + wc * 64 + n * 16 + rr;
            const float bv = bias[col];
#pragma unroll
            for (int j = 0; j < 4; ++j) {
                const int row = m0 + wr * 64 + m * 16 + g * 4 + j;
                const float v = acc[m][n][j] + bv;
                if constexpr (sizeof(OutT) == 2)
                    C[(size_t)row * N + col] = (OutT)f2b(v);
                else
                    C[(size_t)row * N + col] = (OutT)v;
            }
        }
    }
}

// ---------------------------------------------------------------------------
// MFMA causal flash attention — swapped-QK^T, P fully in-register.
// QBLK=64 (4 waves x 16 q-rows), KVBLK=64, paired q-tiles (y, 31-y).
// accT[n][j] = S[q=c][key=n*16+g*4+j] (one q-row per lane -> scalar m,l).
// V stored with bit-permuted columns (vcol) so this lane's packed exp words
// ARE the PV A-fragments: no P LDS buffer, no fences, no tr-reads.
// Double-buffered K/V + register prefetch: ONE barrier per iteration.
// ---------------------------------------------------------------------------
__global__ __launch_bounds__(256, 4)
void attn_mfma(const u16* __restrict__ qkv, u16* __restrict__ out)
{
    __shared__ __align__(128) u16 Ks[2][64 * 64];   // 2 x 8 KB
    __shared__ __align__(128) u16 Vt[2][64 * 64];   // 2 x 8 KB (perm'd cols)

    const int tid  = threadIdx.x;
    const int lane = tid & 63;
    const int wid  = tid >> 6;
    const int c    = lane & 15;       // q-row within wave tile
    const int g    = lane >> 4;

    const int bh = blockIdx.x;        // 0..63
    const int b  = bh >> 4;
    const int h  = bh & 15;

    const int skey = tid >> 3;        // staging key 0..31 (+32 second pass)
    const int sb   = tid & 7;         // staging 16B d-block
    const int kswz = (sb ^ (skey & 7)) * 8;
    const int vswz = ((c & 7) ^ ((/*dn*/0 * 2 + (c >> 3)) & 7));  // per-dn below
    const float QSC = 0.18033688f;    // 0.125 * log2(e)

    // V column permutation: logical key s -> physical column
    auto vcol = [](int s) {
        return (s & 32) | (((s >> 3) & 1) << 4) | (((s >> 2) & 1) << 3)
             | (((s >> 4) & 1) << 2) | (s & 3);
    };

    u16x8 kreg[2], vreg[2];
    const u16* kvbase = qkv + (size_t)b * Tsz * (3 * Csz) + Csz + h * HD + sb * 8;
    auto load_kv = [&](int kt) {
#pragma unroll
        for (int p = 0; p < 2; ++p) {
            const u16* gk = kvbase + (size_t)(kt + skey + p * 32) * (3 * Csz);
            kreg[p] = *reinterpret_cast<const u16x8*>(gk);
            vreg[p] = *reinterpret_cast<const u16x8*>(gk + Csz);
        }
    };

    for (int half = 0; half < 2; ++half) {
        const int yt  = half ? 31 - (int)blockIdx.y : (int)blockIdx.y;
        const int t0  = yt * 64;
        const int qb0 = t0 + wid * 16;     // this wave's 16 q-rows

        // ---- Q fragments (B-operand), pre-scaled by QSC ----
        s16x8 qf[2];
#pragma unroll
        for (int kk = 0; kk < 2; ++kk) {
            u16x8 raw = *reinterpret_cast<const u16x8*>(
                qkv + (size_t)(b * Tsz + qb0 + c) * (3 * Csz) + h * HD + kk * 32 + g * 8);
            s16x8 qv;
#pragma unroll
            for (int i = 0; i < 8; ++i) qv[i] = (short)f2b(b2f(raw[i]) * QSC);
            qf[kk] = qv;
        }

        f32x4 acco[4];
#pragma unroll
        for (int dn = 0; dn < 4; ++dn) acco[dn] = (f32x4){0.f, 0.f, 0.f, 0.f};
        float mrun = -1e30f, lrun = 0.f;

        load_kv(0);   // prologue

        for (int kt = 0; kt <= t0; kt += 64) {
            const int bi = (kt >> 6) & 1;
            // ---- stage K (swizzled b128) + V (perm'd-col scatter) ----
#pragma unroll
            for (int p = 0; p < 2; ++p) {
                const int key = skey + p * 32;
                *reinterpret_cast<u16x8*>(&Ks[bi][key * 64 + kswz]) = kreg[p];
                const int vc = vcol(key);
#pragma unroll
                for (int i = 0; i < 8; ++i) {
                    const int d = sb * 8 + i;
                    Vt[bi][d * 64 + (vc ^ (((i ^ sb) & 7) << 3))] = vreg[p][i];
                }
            }
            if (kt < t0) load_kv(kt + 64);   // prefetch next tile into regs
            __syncthreads();                 // single barrier per iteration

            // ---- S^T: accT[n][j] = S[q=c][key=n*16+g*4+j] (swapped mfma) ----
            f32x4 accT[4];
#pragma unroll
            for (int n = 0; n < 4; ++n) accT[n] = (f32x4){0.f, 0.f, 0.f, 0.f};
            __builtin_amdgcn_s_setprio(1);
#pragma unroll
            for (int kk = 0; kk < 2; ++kk) {
                s16x8 kf[4];
#pragma unroll
                for (int n = 0; n < 4; ++n) {
                    const int key = n * 16 + c;
                    kf[n] = *reinterpret_cast<const s16x8*>(
                        &Ks[bi][key * 64 + (((kk * 4 + g) ^ (c & 7)) * 8)]);
                }
#pragma unroll
                for (int n = 0; n < 4; ++n)
                    accT[n] = __builtin_amdgcn_mfma_f32_16x16x32_bf16(
                        kf[n], qf[kk], accT[n], 0, 0, 0);
            }
            __builtin_amdgcn_s_setprio(0);

            // ---- causal mask (diagonal tile only); q_global = qb0 + c ----
            if (kt == t0) {
#pragma unroll
                for (int n = 0; n < 4; ++n)
#pragma unroll
                    for (int j = 0; j < 4; ++j)
                        if (kt + n * 16 + g * 4 + j > qb0 + c) accT[n][j] = -1e30f;
            }

            // ---- row max: in-register + 2 shfl ----
            float pm = accT[0][0];
#pragma unroll
            for (int n = 0; n < 4; ++n)
#pragma unroll
                for (int j = 0; j < 4; ++j) pm = fmaxf(pm, accT[n][j]);
            pm = fmaxf(pm, __shfl_xor(pm, 16));
            pm = fmaxf(pm, __shfl_xor(pm, 32));

            // ---- defer-max (T13): rescale only if max grew > 8 (log2) ----
            if (__any(pm > mrun + 8.f)) {
                const float mn = fmaxf(mrun, pm);
                const float cv = ex2(mrun - mn);
                mrun = mn;
                lrun *= cv;
                float cvo[4];
#pragma unroll
                for (int j = 0; j < 4; ++j) cvo[j] = __shfl(cv, g * 4 + j);
#pragma unroll
                for (int dn = 0; dn < 4; ++dn)
#pragma unroll
                    for (int j = 0; j < 4; ++j) acco[dn][j] *= cvo[j];
            }

            // ---- P = 2^(S'-m'); packed words ARE the PV A-frags ----
            union { u32 w[8]; s16x8 frag[2]; } pu;
#pragma unroll
            for (int n = 0; n < 4; ++n) {
                const float p0 = ex2(accT[n][0] - mrun);
                const float p1 = ex2(accT[n][1] - mrun);
                const float p2 = ex2(accT[n][2] - mrun);
                const float p3 = ex2(accT[n][3] - mrun);
                lrun += (p0 + p1) + (p2 + p3);
                pu.w[n * 2]     = cvtpk(p0, p1);
                pu.w[n * 2 + 1] = cvtpk(p2, p3);
            }

            // ---- O += P V ----
#pragma unroll
            for (int kk = 0; kk < 2; ++kk) {
                s16x8 vf[4];
#pragma unroll
                for (int dn = 0; dn < 4; ++dn) {
                    const int d = dn * 16 + c;
                    const int swz = (c & 7) ^ ((dn * 2 + (c >> 3)) & 7);
                    vf[dn] = *reinterpret_cast<const s16x8*>(
                        &Vt[bi][d * 64 + (((kk * 4 + g) ^ swz) * 8)]);
                }
                __builtin_amdgcn_s_setprio(1);
#pragma unroll
                for (int dn = 0; dn < 4; ++dn)
                    acco[dn] = __builtin_amdgcn_mfma_f32_16x16x32_bf16(
                        pu.frag[kk], vf[dn], acco[dn], 0, 0, 0);
                __builtin_amdgcn_s_setprio(0);
            }
        }

        // ---- finalize: l-reduce across g-lanes, redistribute, store ----
        lrun += __shfl_xor(lrun, 16);
        lrun += __shfl_xor(lrun, 32);
        const float inv = 1.f / lrun;
        float invo[4];
#pragma unroll
        for (int j = 0; j < 4; ++j) invo[j] = __shfl(inv, g * 4 + j);
#pragma unroll
        for (int dn = 0; dn < 4; ++dn)
#pragma unroll
            for (int j = 0; j < 4; ++j) {
                const int q = qb0 + g * 4 + j;
                out[(size_t)(b * Tsz + q) * Csz + h * HD + dn * 16 + c] =
                    f2b(acco[dn][j] * invo[j]);
            }
        __syncthreads();   // protect LDS before next half restages
    }
    (void)vswz;
}

// ---------------------------------------------------------------------------
extern "C" void kernel_launch(void* const* d_in, const int* in_sizes, int n_in,
                              void* d_out, int out_size, void* d_ws, size_t ws_size,
                              hipStream_t stream) {
    const float* x      = (const float*)d_in[0];   // [B,T,C]
    const float* w_attn = (const float*)d_in[1];   // [C,3C]
    const float* b_attn = (const float*)d_in[2];   // [3C]
    const float* w_proj = (const float*)d_in[3];   // [C,C]
    const float* b_proj = (const float*)d_in[4];   // [C]
    float* out = (float*)d_out;                    // [B,T,C] fp32

    // ws: qkv_bf 48M | x_bf 16M | ao_bf 16M | wat 6M | wpt 2M
    char* w = (char*)d_ws;
    u16* qkv_bf = (u16*)w;  w += (size_t)NT * 3 * Csz * 2;
    u16* x_bf   = (u16*)w;  w += (size_t)NT * Csz * 2;
    u16* ao_bf  = (u16*)w;  w += (size_t)NT * Csz * 2;
    u16* wat    = (u16*)w;  w += (size_t)3 * Csz * Csz * 2;
    u16* wpt    = (u16*)w;

    conv_f32_bf16<<<(NT * Csz / 8 + 255) / 256, 256, 0, stream>>>(x, x_bf, NT * Csz / 8);
    transpose_conv<<<dim3(3 * Csz / 32, Csz / 32), 256, 0, stream>>>(w_attn, wat, Csz, 3 * Csz);
    transpose_conv<<<dim3(Csz / 32, Csz / 32), 256, 0, stream>>>(w_proj, wpt, Csz, Csz);

    gemm_bf16<u16><<<dim3(3 * Csz / 128, NT / 128), 256, 0, stream>>>(
        x_bf, wat, b_attn, qkv_bf, NT, 3 * Csz, Csz);

    attn_mfma<<<dim3(Bsz * NH, 16), 256, 0, stream>>>(qkv_bf, ao_bf);

    gemm_bf16<float><<<dim3(Csz / 128, NT / 128), 256, 0, stream>>>(
        ao_bf, wpt, b_proj, out, NT, Csz, Csz);
}